// Round 5
// baseline (1311.517 us; speedup 1.0000x reference)
//
#include <hip/hip_runtime.h>
#include <stdint.h>

// ---------------------------------------------------------------------------
// SelfConnectionIntro: out[z,w,k] = alpha_l * sum_{u,v} x_l[z,u,k]*o[z,v]*W_l[u,v,w]
// GEMM per path: C[(z,k), w] = A[(z,k), u*16+v] * B[u*16+v, w]
//
// PERSISTENT-B design: B (weights) is small — path1's whole B (1024x64 f16 =
// 128KB) and path2's (32KB) fit LDS; path0 is split into 4 col-slices of
// 2048x32 = 128KB.  Each block loads its B slice ONCE (global_load_lds, one
// barrier), then loops over z-chunks with NO barriers and NO DMA:
//   per tile: x float4 loads (double-buffered groups of 2 tiles) ->
//   in-register A-build (v_pk_mul_f16) -> ds_read B frags -> 16 MFMA.
// A-fragment mapping (verified r3, absmax 0.0156):
//   lane(l16,q): A row=l16, k=q*8+0..7; window 32k = 2u x 16v =>
//   u = 4t + 2h + (q>>1) (one x scalar), v = (q&1)*8 + j (8 consecutive o).
// B LDS layout: [tile t][ncol][64] with XOR swizzle c ^= (n&7)*8 (0 conflicts).
// LDS is STATIC 128 KiB (r4 used dynamic -> possible launch-limit wedge).
// ---------------------------------------------------------------------------

typedef __attribute__((ext_vector_type(8))) _Float16 f16x8;  // MFMA frag (4 VGPR)
typedef __attribute__((ext_vector_type(2))) _Float16 f16x2;  // v_pk_mul_f16 pair
typedef __attribute__((ext_vector_type(4))) float f32x4;

// --- prep: f16(W), tile-major XOR-swizzled; path0 additionally slice-major --
__global__ void prep_wt(const float* __restrict__ w0, const float* __restrict__ w1,
                        const float* __restrict__ w2, unsigned short* __restrict__ wt) {
    int i = blockIdx.x * 256 + threadIdx.x;
    int idx; float v;
    if (i < 262144) {                               // path0: K=2048, 128 cols, 4 slices of 32
        int n = i >> 11, kk = i & 2047;
        int slice = n >> 5, nn = n & 31;
        int t = kk >> 6, c = kk & 63;
        v = w0[kk * 128 + n];
        idx = slice * 65536 + t * 2048 + nn * 64 + (c ^ ((nn & 7) * 8));
    } else if (i < 327680) {                        // path1: K=1024, 64 cols (whole B)
        int r = i - 262144;
        int n = r >> 10, kk = r & 1023;
        int t = kk >> 6, c = kk & 63;
        v = w1[kk * 64 + n];
        idx = 262144 + t * 4096 + n * 64 + (c ^ ((n & 7) * 8));
    } else {                                        // path2: K=512, 32 cols (whole B)
        int r = i - 327680;
        int n = r >> 9, kk = r & 511;
        int t = kk >> 6, c = kk & 63;
        v = w2[kk * 32 + n];
        idx = 327680 + t * 2048 + n * 64 + (c ^ ((n & 7) * 8));
    }
    union { _Float16 h; unsigned short s; } u;
    u.h = (_Float16)v;
    wt[idx] = u.s;
}

__device__ __forceinline__ void gl_lds16(const void* g, void* l) {
    __builtin_amdgcn_global_load_lds(
        (const __attribute__((address_space(1))) unsigned int*)g,
        (__attribute__((address_space(3))) unsigned int*)l, 16, 0, 0);
}

// --- per-path persistent-B worker -------------------------------------------
// D=2l+1, OFF=slice offset in x/out rows, K=u*16, BCOL=cols in LDS,
// WM x WN = 8-wave grid.  TM=4 (64 rows/wave), TN=BCOL/(WN*16)=2.
template<int D, int OFF, int K, int BCOL, int WM, int WN>
__device__ __forceinline__ void path_persist(int zb, int NZB, int colbase,
        const float* __restrict__ x, const float* __restrict__ op,
        const unsigned short* __restrict__ wt, float* __restrict__ out,
        int Z, float alpha, unsigned short* Bsm)
{
    constexpr int KT  = K / 64;                 // 64-k tiles (32/16/8)
    constexpr int NG  = KT / 2;                 // groups of 2 tiles (16/8/4, even)
    constexpr int TM  = 4;
    constexpr int TN  = BCOL / (WN * 16);       // 2 everywhere
    constexpr int CH  = WM * 64;                // chunk rows (512/256/512)
    constexpr int TSH = K * BCOL;               // B shorts (65536/65536/16384)
    constexpr int NIT = TSH / (512 * 8);        // DMA iters (16/16/4)
    constexpr int XW  = (D == 1) ? 4 : 2;
    constexpr int TILE = BCOL * 64;             // shorts per tile

    const int tid  = threadIdx.x;
    const int lane = tid & 63, wv = tid >> 6;
    const int q    = lane >> 4, l16 = lane & 15;
    const int qh   = q >> 1;                    // which u in a 2u window
    const int vh   = (q & 1) * 8;               // lane's o half
    const int wm0  = (wv / WN) * 64;
    const int wn0  = (wv % WN) * 32;
    const int M    = Z * D;
    const char* xb = (const char*)x;

    // ---- load B slice into LDS once ----
    #pragma unroll
    for (int it = 0; it < NIT; ++it) {
        int off = it * 4096 + tid * 8;          // lane*16B contiguous per wave
        gl_lds16(wt + off, Bsm + off);
    }
    __syncthreads();                            // only barrier in the kernel

    const int nch = (M + CH - 1) / CH;
    const int c0 = (int)((long)zb * nch / NZB);
    const int c1 = (int)((long)(zb + 1) * nch / NZB);

    for (int c = c0; c < c1; ++c) {
        const long base = (long)c * CH;

        // ---- per-row setup: x byte-offset + o regs (lane's v-half) ----
        int xoff[TM];
        f16x2 oh[TM][4];
        #pragma unroll
        for (int i = 0; i < TM; ++i) {
            long m = base + wm0 + i * 16 + l16;
            if (m >= M) m = M - 1;              // clamp (stores guarded)
            int z = (int)(m / D), kr = (int)(m % D);
            xoff[i] = z * 1920 + (OFF + kr) * 4 + (D > 1 ? qh * D * 4 : 0);
            const f32x4* o4 = (const f32x4*)(op + (size_t)z * 16 + vh);
            f32x4 oa = o4[0], ob = o4[1];
            oh[i][0] = f16x2{(_Float16)oa[0], (_Float16)oa[1]};
            oh[i][1] = f16x2{(_Float16)oa[2], (_Float16)oa[3]};
            oh[i][2] = f16x2{(_Float16)ob[0], (_Float16)ob[1]};
            oh[i][3] = f16x2{(_Float16)ob[2], (_Float16)ob[3]};
        }

        f32x4 acc[TM][TN];
        #pragma unroll
        for (int i = 0; i < TM; ++i)
            #pragma unroll
            for (int j = 0; j < TN; ++j) acc[i][j] = f32x4{0.f, 0.f, 0.f, 0.f};

        float xr0[2][TM][XW], xr1[2][TM][XW];   // static ping-pong (rule #20)

        auto xloadA = [&](int g) {
            #pragma unroll
            for (int tt = 0; tt < 2; ++tt) {
                int t = g * 2 + tt;
                #pragma unroll
                for (int i = 0; i < TM; ++i) {
                    if constexpr (D == 1) {
                        f32x4 xv = *(const f32x4*)(xb + xoff[i] + t * 16);
                        xr0[tt][i][0] = xv[0]; xr0[tt][i][1] = xv[1];
                        xr0[tt][i][2] = xv[2]; xr0[tt][i][3] = xv[3];
                    } else {
                        xr0[tt][i][0] = *(const float*)(xb + xoff[i] + (t * 4    ) * D * 4);
                        xr0[tt][i][1] = *(const float*)(xb + xoff[i] + (t * 4 + 2) * D * 4);
                    }
                }
            }
        };
        auto xloadB = [&](int g) {
            #pragma unroll
            for (int tt = 0; tt < 2; ++tt) {
                int t = g * 2 + tt;
                #pragma unroll
                for (int i = 0; i < TM; ++i) {
                    if constexpr (D == 1) {
                        f32x4 xv = *(const f32x4*)(xb + xoff[i] + t * 16);
                        xr1[tt][i][0] = xv[0]; xr1[tt][i][1] = xv[1];
                        xr1[tt][i][2] = xv[2]; xr1[tt][i][3] = xv[3];
                    } else {
                        xr1[tt][i][0] = *(const float*)(xb + xoff[i] + (t * 4    ) * D * 4);
                        xr1[tt][i][1] = *(const float*)(xb + xoff[i] + (t * 4 + 2) * D * 4);
                    }
                }
            }
        };
        auto computeA = [&](int g) {
            #pragma unroll
            for (int tt = 0; tt < 2; ++tt) {
                const unsigned short* tb = Bsm + (g * 2 + tt) * TILE;
                #pragma unroll
                for (int h = 0; h < 2; ++h) {
                    f16x8 bfr[TN];
                    #pragma unroll
                    for (int j = 0; j < TN; ++j) {
                        int n = wn0 + j * 16 + l16;
                        bfr[j] = *(const f16x8*)(tb + n * 64 + ((h * 32 + q * 8) ^ ((n & 7) * 8)));
                    }
                    #pragma unroll
                    for (int i = 0; i < TM; ++i) {
                        float xs;
                        if constexpr (D == 1) xs = qh ? xr0[tt][i][h * 2 + 1] : xr0[tt][i][h * 2];
                        else                  xs = xr0[tt][i][h];
                        _Float16 xh = (_Float16)xs;
                        f16x2 xx{xh, xh};
                        unsigned int pk[4];
                        #pragma unroll
                        for (int j2 = 0; j2 < 4; ++j2)
                            pk[j2] = __builtin_bit_cast(unsigned int, xx * oh[i][j2]);
                        f16x8 af = __builtin_bit_cast(f16x8, uint4{pk[0], pk[1], pk[2], pk[3]});
                        #pragma unroll
                        for (int j = 0; j < TN; ++j)
                            acc[i][j] = __builtin_amdgcn_mfma_f32_16x16x32_f16(
                                af, bfr[j], acc[i][j], 0, 0, 0);
                    }
                }
            }
        };
        auto computeB = [&](int g) {
            #pragma unroll
            for (int tt = 0; tt < 2; ++tt) {
                const unsigned short* tb = Bsm + (g * 2 + tt) * TILE;
                #pragma unroll
                for (int h = 0; h < 2; ++h) {
                    f16x8 bfr[TN];
                    #pragma unroll
                    for (int j = 0; j < TN; ++j) {
                        int n = wn0 + j * 16 + l16;
                        bfr[j] = *(const f16x8*)(tb + n * 64 + ((h * 32 + q * 8) ^ ((n & 7) * 8)));
                    }
                    #pragma unroll
                    for (int i = 0; i < TM; ++i) {
                        float xs;
                        if constexpr (D == 1) xs = qh ? xr1[tt][i][h * 2 + 1] : xr1[tt][i][h * 2];
                        else                  xs = xr1[tt][i][h];
                        _Float16 xh = (_Float16)xs;
                        f16x2 xx{xh, xh};
                        unsigned int pk[4];
                        #pragma unroll
                        for (int j2 = 0; j2 < 4; ++j2)
                            pk[j2] = __builtin_bit_cast(unsigned int, xx * oh[i][j2]);
                        f16x8 af = __builtin_bit_cast(f16x8, uint4{pk[0], pk[1], pk[2], pk[3]});
                        #pragma unroll
                        for (int j = 0; j < TN; ++j)
                            acc[i][j] = __builtin_amdgcn_mfma_f32_16x16x32_f16(
                                af, bfr[j], acc[i][j], 0, 0, 0);
                    }
                }
            }
        };

        // ---- barrier-free K loop: 2-unrolled group ping-pong ----
        xloadA(0);
        for (int g = 0; g < NG; g += 2) {
            xloadB(g + 1);
            computeA(g);
            if (g + 2 < NG) xloadA(g + 2);
            computeB(g + 1);
        }

        // ---- stores: C/D layout col=lane&15, row=q*4+reg (m89-verified) ----
        #pragma unroll
        for (int i = 0; i < TM; ++i) {
            #pragma unroll
            for (int p = 0; p < 4; ++p) {
                long m = base + wm0 + i * 16 + q * 4 + p;
                if (m < M) {
                    int z = (int)(m / D), k = (int)(m % D);
                    float* orow = out + (size_t)z * 480 + OFF + k;
                    #pragma unroll
                    for (int j = 0; j < TN; ++j) {
                        int col = colbase + wn0 + j * 16 + l16;
                        orow[(size_t)col * D] = alpha * acc[i][j][p];
                    }
                }
            }
        }
    }
}

// --- fused kernel: one dispatch, branch per block on (path, slice, z-range) --
__global__ __launch_bounds__(512, 1)
void fctp_persist(const float* __restrict__ x, const float* __restrict__ op,
                  const unsigned short* __restrict__ wt, float* __restrict__ out,
                  int Z, int nb0, int nb01, int nbtot) {
    __shared__ unsigned short Bsm[65536];       // 128 KiB STATIC
    int bid = blockIdx.x;
    if (bid < nb0) {                            // path0: 4 col-slices x z-blocks
        int zb = bid >> 2, slice = bid & 3;     // adjacent slices share z-range (L3)
        path_persist<1, 0, 2048, 32, 8, 1>(zb, nb0 >> 2, slice * 32, x, op,
                wt + slice * 65536, out, Z, 0.02209708691f, Bsm);
    } else if (bid < nb01) {                    // path1: whole B resident
        path_persist<3, 128, 1024, 64, 4, 2>(bid - nb0, nb01 - nb0, 0, x, op,
                wt + 262144, out, Z, 0.03125f, Bsm);
    } else {                                    // path2: whole B resident
        path_persist<5, 320, 512, 32, 8, 1>(bid - nb01, nbtot - nb01, 0, x, op,
                wt + 327680, out, Z, 0.04419417382f, Bsm);
    }
}

extern "C" void kernel_launch(void* const* d_in, const int* in_sizes, int n_in,
                              void* d_out, int out_size, void* d_ws, size_t ws_size,
                              hipStream_t stream) {
    (void)n_in; (void)out_size; (void)ws_size;
    const float* x  = (const float*)d_in[0];
    const float* op = (const float*)d_in[1];
    const float* w0 = (const float*)d_in[2];
    const float* w1 = (const float*)d_in[3];
    const float* w2 = (const float*)d_in[4];
    float* out = (float*)d_out;
    const int Z = in_sizes[0] / 480;

    unsigned short* wt = (unsigned short*)d_ws;    // 344064 f16 = 688128 B
    prep_wt<<<1344, 256, 0, stream>>>(w0, w1, w2, wt);

    // work-balanced grid (~FLOP ratio 48.5/36.4/15.2%): 448 + 384 + 192 = 1024
    const int nb0   = 448;                      // 112 z-blocks x 4 slices
    const int nb01  = nb0 + 384;
    const int nbtot = nb01 + 192;
    fctp_persist<<<nbtot, 512, 0, stream>>>(x, op, wt, out, Z, nb0, nb01, nbtot);
}